// Round 6
// baseline (784.836 us; speedup 1.0000x reference)
//
#include <hip/hip_runtime.h>
#include <hip/hip_bf16.h>
#include <math.h>

// Problem constants
#define BB 4
#define SS 2048
#define EE 1024
#define HH 16
#define DD 64
#define FF 4096

typedef unsigned short u16;
typedef unsigned int u32;
typedef __bf16 bf16x8 __attribute__((ext_vector_type(8)));
typedef float f32x4 __attribute__((ext_vector_type(4)));

static __device__ __forceinline__ float gelu_exact(float v){
  return 0.5f * v * (1.0f + erff(v * 0.70710678118654752f));
}

// float -> bf16 (RNE)
static __device__ __forceinline__ u16 f2bf(float f){
  union { float f; u32 u; } x; x.f = f;
  u32 r = x.u + 0x7FFFu + ((x.u >> 16) & 1u);
  return (u16)(r >> 16);
}
// unpack a u32 holding two bf16 (little-endian: elem0 = low half)
static __device__ __forceinline__ void unpack2(u32 u, float& lo, float& hi){
  union { u32 u; float f; } a, b;
  a.u = u << 16; b.u = u & 0xFFFF0000u;
  lo = a.f; hi = b.f;
}

#define GLOAD_LDS16(g, l) \
  __builtin_amdgcn_global_load_lds((const __attribute__((address_space(1))) void*)(g), \
      (__attribute__((address_space(3))) void*)(l), 16, 0, 0)

// ---------------- embedding gather: write f32 (for residual) + bf16 (GEMM A) ----------------
__global__ __launch_bounds__(256) void embed_kernel(const int* __restrict__ ids,
    const float* __restrict__ emb, float* __restrict__ xf, u16* __restrict__ xbf){
  int row = blockIdx.x;
  int id  = ids[row];
  float4 v = ((const float4*)(emb + (size_t)id * EE))[threadIdx.x];
  ((float4*)(xf + (size_t)row * EE))[threadIdx.x] = v;
  ushort4 u; u.x = f2bf(v.x); u.y = f2bf(v.y); u.z = f2bf(v.z); u.w = f2bf(v.w);
  ((ushort4*)(xbf + (size_t)row * EE))[threadIdx.x] = u;
}

// ---------------- fused weight prep: all 5 transposes in one dispatch ----------------
// WT base layout: WqT,WkT,WvT,WoT (each [EE][EE]) then W1T ([FF][EE]), contiguous.
__global__ __launch_bounds__(256) void prep_weights(const float* __restrict__ Wq,
    const float* __restrict__ Wk, const float* __restrict__ Wv,
    const float* __restrict__ Wo, const float* __restrict__ W1, u16* __restrict__ WT){
  __shared__ float tile[32][33];
  int bid = blockIdx.x;
  const float* W; u16* dst; int N, n0, k0;
  if (bid < 4096){
    W = W1; dst = WT + (size_t)4 * EE * EE; N = FF;
    n0 = (bid & 127) * 32; k0 = (bid >> 7) * 32;
  } else {
    int idx = bid - 4096;
    int which = idx >> 10, t = idx & 1023;
    W = (which == 0) ? Wq : (which == 1) ? Wk : (which == 2) ? Wv : Wo;
    dst = WT + (size_t)which * EE * EE; N = EE;
    n0 = (t & 31) * 32; k0 = (t >> 5) * 32;
  }
  int tx = threadIdx.x & 31, ty = threadIdx.x >> 5;   // ty 0..7
  #pragma unroll
  for (int i = 0; i < 4; i++)
    tile[ty + 8*i][tx] = W[(size_t)(k0 + ty + 8*i) * N + n0 + tx];
  __syncthreads();
  #pragma unroll
  for (int i = 0; i < 4; i++)
    dst[(size_t)(n0 + ty + 8*i) * EE + k0 + tx] = f2bf(tile[tx][ty + 8*i]);
}

// ---------------- bf16 MFMA GEMM v2: A-frags direct from global, B dbuf LDS ----------------
// A: bf16 row-major [M,K]. WT: bf16 [N,K]. 128x128 tile, BK=32, ONE barrier/iter.
// A-fragment = 16B contiguous row-chunk -> global_load_dwordx4 per lane, L1/L2
// served (consecutive blockIdx.x share A rows; wave pairs read identical frags).
// B staged via global_load_lds into double-buffered Bs, prefetch issued right
// after the barrier so it has the whole body to land.
// MODE 0: store bf16 C.
// MODE 1: gelu + per-batch column-sum atomics into gsum[B][N].
// MODE 2: fused QKV (WT spans 3N rows; slab sel = col>>10; bias from {a,b,c}).
template<int MODE>
__global__ __launch_bounds__(256) void gemm_mfma(const u16* __restrict__ A,
    const u16* __restrict__ WT, const float* __restrict__ bias,
    const float* __restrict__ biasB, const float* __restrict__ biasC,
    u16* __restrict__ C, float* __restrict__ gsum, int M, int N, int K){
  __shared__ __attribute__((aligned(16))) u16 Bs[2][128 * 32];   // 16 KB

  const int tid = threadIdx.x;
  const int l = tid & 63, w = tid >> 6;
  const int lm = l & 15, lq = l >> 4;
  const int wm = (w >> 1) * 64, wn = (w & 1) * 64;
  const int r0 = blockIdx.y * 128, c0 = blockIdx.x * 128;

  const int srow0 = w * 32 + (l >> 2);          // B staging row for instr 0
  const int scol  = (l & 3) * 8;
  const u16* Bb = WT + (size_t)(c0 + srow0) * K + scol;
  const u16* Ab = A  + (size_t)(r0 + wm + lm) * K + lq * 8;   // + mi*16*K + it*32

  f32x4 acc[4][4];
  const f32x4 zero = {0.f, 0.f, 0.f, 0.f};
  #pragma unroll
  for (int mi = 0; mi < 4; mi++)
    #pragma unroll
    for (int ni = 0; ni < 4; ni++) acc[mi][ni] = zero;

  // prefetch iter 0: A-frags into regs, B via async LDS DMA
  bf16x8 acur[4], anext[4];
  #pragma unroll
  for (int mi = 0; mi < 4; mi++)
    acur[mi] = *(const bf16x8*)(Ab + (size_t)(mi * 16) * K);
  GLOAD_LDS16(Bb,                  &Bs[0][(w * 2)     * 512]);
  GLOAD_LDS16(Bb + (size_t)16 * K, &Bs[0][(w * 2 + 1) * 512]);

  const int NIT = K / 32;
  for (int it = 0; it < NIT; it++){
    __syncthreads();                 // Bs[it&1] staged (vmcnt drain at barrier)
    if (it + 1 < NIT){
      GLOAD_LDS16(Bb + (size_t)(it + 1) * 32,
                  &Bs[(it + 1) & 1][(w * 2)     * 512]);
      GLOAD_LDS16(Bb + (size_t)16 * K + (size_t)(it + 1) * 32,
                  &Bs[(it + 1) & 1][(w * 2 + 1) * 512]);
      #pragma unroll
      for (int mi = 0; mi < 4; mi++)
        anext[mi] = *(const bf16x8*)(Ab + (size_t)(mi * 16) * K + (size_t)(it + 1) * 32);
    }
    bf16x8 bf[4];
    #pragma unroll
    for (int ni = 0; ni < 4; ni++)
      bf[ni] = *(const bf16x8*)&Bs[it & 1][(wn + ni*16 + lm) * 32 + lq * 8];
    #pragma unroll
    for (int mi = 0; mi < 4; mi++)
      #pragma unroll
      for (int ni = 0; ni < 4; ni++)
        acc[mi][ni] = __builtin_amdgcn_mfma_f32_16x16x32_bf16(acur[mi], bf[ni], acc[mi][ni], 0, 0, 0);
    #pragma unroll
    for (int mi = 0; mi < 4; mi++) acur[mi] = anext[mi];
  }

  // C/D layout (verified m89/m91): col = lane&15, row = (lane>>4)*4 + reg
  if constexpr (MODE == 0){
    #pragma unroll
    for (int ni = 0; ni < 4; ni++){
      int col = c0 + wn + ni*16 + lm;
      float bcol = bias[col];
      #pragma unroll
      for (int mi = 0; mi < 4; mi++){
        #pragma unroll
        for (int r = 0; r < 4; r++){
          int row = r0 + wm + mi*16 + lq*4 + r;
          C[(size_t)row * N + col] = f2bf(acc[mi][ni][r] + bcol);
        }
      }
    }
  } else if constexpr (MODE == 2){
    #pragma unroll
    for (int ni = 0; ni < 4; ni++){
      int col3 = c0 + wn + ni*16 + lm;      // never crosses a 1024 boundary within 16
      int sel  = col3 >> 10;
      int colm = col3 & 1023;
      const float* bp_ = (sel == 0) ? bias : ((sel == 1) ? biasB : biasC);
      float bcol = bp_[colm];
      u16* dst = C + (size_t)sel * ((size_t)M * N);
      #pragma unroll
      for (int mi = 0; mi < 4; mi++){
        #pragma unroll
        for (int r = 0; r < 4; r++){
          int row = r0 + wm + mi*16 + lq*4 + r;
          dst[(size_t)row * N + colm] = f2bf(acc[mi][ni][r] + bcol);
        }
      }
    }
  } else {
    const int batch = r0 >> 11;   // 2048 rows per batch, 128 | 2048
    #pragma unroll
    for (int ni = 0; ni < 4; ni++){
      int col = c0 + wn + ni*16 + lm;
      float bcol = bias[col];
      float cs = 0.f;
      #pragma unroll
      for (int mi = 0; mi < 4; mi++)
        #pragma unroll
        for (int r = 0; r < 4; r++)
          cs += gelu_exact(acc[mi][ni][r] + bcol);
      cs += __shfl_xor(cs, 16, 64);
      cs += __shfl_xor(cs, 32, 64);
      if (lq == 0) atomicAdd(&gsum[(size_t)batch * N + col], cs);
    }
  }
}

// ---------------- MFMA flash attention v3 ----------------
// Block: one (b,h), 128 q-rows; 4 waves x 32 q-rows; 256 threads. 64-key tiles.
// K-frags loaded DIRECT from global ([key][d] layout -> 16B row-chunks; all 4
// waves read identical addresses -> L1-served). Kt removed; Vt double-buffered
// -> ONE barrier per tile. V commit from registers prefetched one tile ahead.
// No-max softmax in exp2 domain (scores O(1e-3); clamp guards overflow).
__global__ __launch_bounds__(256) void attn_mfma(const u16* __restrict__ q,
    const u16* __restrict__ k, const u16* __restrict__ v,
    const int* __restrict__ mask, u16* __restrict__ ctx){
  const int bh = blockIdx.y, b = bh >> 4, h = bh & 15;
  const int q0 = blockIdx.x * 128;
  const int tid = threadIdx.x;
  const int w = tid >> 6, l = tid & 63, lm = l & 15, lq = l >> 4;

  __shared__ __attribute__((aligned(16))) u16 Vt[2][64 * 72];
  __shared__ __attribute__((aligned(16))) u16 Pw[4][32 * 72];
  __shared__ float mb[2][64];

  // Q A-frags direct from global: A[m=lane&15][k=quad*8+j]; 2 row-groups/wave
  bf16x8 aq[2][2];
  #pragma unroll
  for (int mg = 0; mg < 2; mg++){
    const u16* qrow = q + (size_t)(b*SS + q0 + w*32 + mg*16 + lm) * EE + h*DD + lq*8;
    aq[mg][0] = *(const bf16x8*)qrow;
    aq[mg][1] = *(const bf16x8*)(qrow + 32);
  }

  f32x4 occ[2][4];
  const f32x4 zero = {0.f,0.f,0.f,0.f};
  #pragma unroll
  for (int mg = 0; mg < 2; mg++)
    #pragma unroll
    for (int ni = 0; ni < 4; ni++) occ[mg][ni] = zero;
  float l_part[2][4] = {{0.f,0.f,0.f,0.f},{0.f,0.f,0.f,0.f}};

  // V staging coords: thread covers keys {2kp, 2kp+1} x 8 d-values
  const int kp = tid & 31, vd0 = (tid >> 5) * 8;
  const u16* vbase0 = v + (size_t)(b*SS + 2*kp) * EE + h*DD + vd0;
  const u16* vbase1 = vbase0 + EE;
  // K-frag base: row lm within each 16-key group, d-chunk lq*8
  const u16* kfbase = k + (size_t)(b*SS + lm) * EE + h*DD + lq*8;

  // prefetch tile 0
  uint4 vr0 = *(const uint4*)(vbase0);
  uint4 vr1 = *(const uint4*)(vbase1);
  float mreg = 0.f;
  if (tid < 64) mreg = (mask[b*SS + tid] != 0) ? 0.f : -1e30f;

  const float SCALE_LOG2E = 0.125f * 1.4426950408889634f;
  const int NT = SS / 64;

  for (int it = 0; it < NT; it++){
    const int t0 = it * 64;
    // commit prefetched V regs -> Vt[it&1] (transposed, packed b32 key-pairs)
    {
      union { uint4 u; u16 s[8]; } va, vb_;
      va.u = vr0; vb_.u = vr1;
      #pragma unroll
      for (int i = 0; i < 8; i++){
        u32 pk = (u32)va.s[i] | ((u32)vb_.s[i] << 16);
        *(u32*)&Vt[it & 1][(vd0 + i)*72 + 2*kp] = pk;
      }
    }
    if (tid < 64) mb[it & 1][tid] = mreg;
    __syncthreads();                       // single barrier per tile

    // prefetch next tile's V + mask (lands during compute)
    if (it + 1 < NT){
      vr0 = *(const uint4*)(vbase0 + (size_t)(t0 + 64) * EE);
      vr1 = *(const uint4*)(vbase1 + (size_t)(t0 + 64) * EE);
      if (tid < 64) mreg = (mask[b*SS + t0 + 64 + tid] != 0) ? 0.f : -1e30f;
    }

    // K-frags direct from global (identical across waves -> L1 hits)
    bf16x8 kf0[4], kf1[4];
    #pragma unroll
    for (int ni = 0; ni < 4; ni++){
      const u16* kr = kfbase + (size_t)(t0 + ni*16) * EE;
      kf0[ni] = *(const bf16x8*)kr;
      kf1[ni] = *(const bf16x8*)(kr + 32);
    }

    // QK^T + softmax + P-write per row-group
    #pragma unroll
    for (int mg = 0; mg < 2; mg++){
      #pragma unroll
      for (int ni = 0; ni < 4; ni++){
        f32x4 sc = zero;
        sc = __builtin_amdgcn_mfma_f32_16x16x32_bf16(aq[mg][0], kf0[ni], sc, 0, 0, 0);
        sc = __builtin_amdgcn_mfma_f32_16x16x32_bf16(aq[mg][1], kf1[ni], sc, 0, 0, 0);
        float mbias = mb[it & 1][ni*16 + lm];
        #pragma unroll
        for (int r = 0; r < 4; r++){
          float s = fminf(fmaf(sc[r], SCALE_LOG2E, mbias), 80.f);
          float p = __builtin_amdgcn_exp2f(s);
          l_part[mg][r] += p;
          Pw[w][(mg*16 + lq*4 + r)*72 + ni*16 + lm] = f2bf(p);
        }
      }
    }
    // P: C-layout -> A-layout via wave-private LDS (no barrier needed)
    bf16x8 ap[2][2];
    #pragma unroll
    for (int mg = 0; mg < 2; mg++){
      ap[mg][0] = *(const bf16x8*)&Pw[w][(mg*16 + lm)*72 + lq*8];
      ap[mg][1] = *(const bf16x8*)&Pw[w][(mg*16 + lm)*72 + 32 + lq*8];
    }

    // PV: B-frags from Vt[d][key], shared across both row-groups
    #pragma unroll
    for (int ni = 0; ni < 4; ni++){
      bf16x8 vb0 = *(const bf16x8*)&Vt[it & 1][(ni*16 + lm)*72 + lq*8];
      bf16x8 vb1 = *(const bf16x8*)&Vt[it & 1][(ni*16 + lm)*72 + 32 + lq*8];
      #pragma unroll
      for (int mg = 0; mg < 2; mg++){
        occ[mg][ni] = __builtin_amdgcn_mfma_f32_16x16x32_bf16(ap[mg][0], vb0, occ[mg][ni], 0, 0, 0);
        occ[mg][ni] = __builtin_amdgcn_mfma_f32_16x16x32_bf16(ap[mg][1], vb1, occ[mg][ni], 0, 0, 0);
      }
    }
    // no trailing barrier: next commit targets the other Vt buffer
  }

  // final l reduction across the 16-lane column group, once
  #pragma unroll
  for (int mg = 0; mg < 2; mg++){
    float inv[4];
    #pragma unroll
    for (int r = 0; r < 4; r++){
      float s = l_part[mg][r];
      s += __shfl_xor(s, 1, 64);
      s += __shfl_xor(s, 2, 64);
      s += __shfl_xor(s, 4, 64);
      s += __shfl_xor(s, 8, 64);
      inv[r] = 1.f / s;
    }
    #pragma unroll
    for (int ni = 0; ni < 4; ni++){
      int col = h*DD + ni*16 + lm;
      #pragma unroll
      for (int r = 0; r < 4; r++){
        int row = q0 + w*32 + mg*16 + lq*4 + r;
        ctx[(size_t)(b*SS + row) * EE + col] = f2bf(occ[mg][ni][r] * inv[r]);
      }
    }
  }
}

// ---------------- fused residual + LayerNorm (bf16 ctx2 in, bf16 h out) ----------------
__global__ __launch_bounds__(256) void ln_kernel(const u16* __restrict__ c2,
    const float* __restrict__ x, const float* __restrict__ g,
    const float* __restrict__ bta, u16* __restrict__ h){
  int row = blockIdx.x, tid = threadIdx.x;
  uint2 cu = ((const uint2*)(c2 + (size_t)row * EE))[tid];
  float c0,c1,c2f,c3;
  unpack2(cu.x, c0, c1); unpack2(cu.y, c2f, c3);
  float4 xv = ((const float4*)(x + (size_t)row * EE))[tid];
  float4 y = make_float4(c0+xv.x, c1+xv.y, c2f+xv.z, c3+xv.w);
  float s  = y.x + y.y + y.z + y.w;
  float ss = y.x*y.x + y.y*y.y + y.z*y.z + y.w*y.w;
  #pragma unroll
  for (int off=32; off; off>>=1){
    s  += __shfl_xor(s,  off, 64);
    ss += __shfl_xor(ss, off, 64);
  }
  __shared__ float rs[4], rss[4];
  int w = tid >> 6;
  if ((tid & 63) == 0){ rs[w] = s; rss[w] = ss; }
  __syncthreads();
  float tot  = rs[0]+rs[1]+rs[2]+rs[3];
  float tots = rss[0]+rss[1]+rss[2]+rss[3];
  float mu  = tot  * (1.f/EE);
  float var = tots * (1.f/EE) - mu*mu;
  float inv = rsqrtf(var + 1e-5f);
  float4 gv = ((const float4*)g)[tid];
  float4 bv = ((const float4*)bta)[tid];
  ushort4 ou;
  ou.x = f2bf((y.x-mu)*inv*gv.x + bv.x);
  ou.y = f2bf((y.y-mu)*inv*gv.y + bv.y);
  ou.z = f2bf((y.z-mu)*inv*gv.z + bv.z);
  ou.w = f2bf((y.w-mu)*inv*gv.w + bv.w);
  ((ushort4*)(h + (size_t)row * EE))[tid] = ou;
}

// ---------------- W2Wp[f][j] = sum_e W2[f][e] * Wp[e][j] ----------------
__global__ __launch_bounds__(256) void w2wp_kernel(const float* __restrict__ W2,
    const float* __restrict__ Wp, float* __restrict__ W2Wp){
  int f0 = blockIdx.x * 8;
  int tid = threadIdx.x;
  int e0 = tid * 4;
  float wp[4][3];
  #pragma unroll
  for (int t = 0; t < 4; t++)
    #pragma unroll
    for (int j = 0; j < 3; j++) wp[t][j] = Wp[(e0 + t)*3 + j];
  __shared__ float red[3][4];
  for (int i = 0; i < 8; i++){
    int f = f0 + i;
    float4 wv = ((const float4*)(W2 + (size_t)f * EE))[tid];
    float w4[4] = {wv.x, wv.y, wv.z, wv.w};
    float p[3] = {0.f, 0.f, 0.f};
    #pragma unroll
    for (int t = 0; t < 4; t++)
      #pragma unroll
      for (int j = 0; j < 3; j++) p[j] += w4[t] * wp[t][j];
    #pragma unroll
    for (int j = 0; j < 3; j++){
      float sj = p[j];
      #pragma unroll
      for (int off = 32; off; off >>= 1) sj += __shfl_xor(sj, off, 64);
      if ((tid & 63) == 0) red[j][tid >> 6] = sj;
    }
    __syncthreads();
    if (tid < 3) W2Wp[f*3 + tid] = red[tid][0] + red[tid][1] + red[tid][2] + red[tid][3];
    __syncthreads();
  }
}

// ---------------- out[b,j] = sum_f (gsum[b,f]/S) W2Wp[f,j] + (b2@Wp)[j] + bp[j] ----------------
__global__ __launch_bounds__(256) void out_final(const float* __restrict__ gsum,
    const float* __restrict__ W2Wp, const float* __restrict__ b2,
    const float* __restrict__ Wp, const float* __restrict__ bp, float* __restrict__ out){
  int tid = threadIdx.x;
  float part[4][3];
  #pragma unroll
  for (int b = 0; b < 4; b++)
    #pragma unroll
    for (int j = 0; j < 3; j++) part[b][j] = 0.f;
  for (int f = tid; f < FF; f += 256){
    float w0 = W2Wp[f*3], w1 = W2Wp[f*3+1], w2v = W2Wp[f*3+2];
    #pragma unroll
    for (int b = 0; b < 4; b++){
      float g = gsum[b*FF + f] * (1.f/SS);
      part[b][0] += g * w0; part[b][1] += g * w1; part[b][2] += g * w2v;
    }
  }
  float bb[3] = {0.f, 0.f, 0.f};
  for (int e = tid; e < EE; e += 256){
    float bv = b2[e];
    bb[0] += bv * Wp[e*3]; bb[1] += bv * Wp[e*3+1]; bb[2] += bv * Wp[e*3+2];
  }
  __shared__ float red[15][4];
  int lane = tid & 63, w = tid >> 6;
  #pragma unroll
  for (int b = 0; b < 4; b++)
    #pragma unroll
    for (int j = 0; j < 3; j++){
      float s = part[b][j];
      #pragma unroll
      for (int off = 32; off; off >>= 1) s += __shfl_xor(s, off, 64);
      if (lane == 0) red[b*3 + j][w] = s;
    }
  #pragma unroll
  for (int j = 0; j < 3; j++){
    float s = bb[j];
    #pragma unroll
    for (int off = 32; off; off >>= 1) s += __shfl_xor(s, off, 64);
    if (lane == 0) red[12 + j][w] = s;
  }
  __syncthreads();
  if (tid < 12){
    int j = tid % 3;
    float s  = red[tid][0] + red[tid][1] + red[tid][2] + red[tid][3];
    float bj = red[12+j][0] + red[12+j][1] + red[12+j][2] + red[12+j][3];
    out[tid] = s + bj + bp[j];
  }
}

extern "C" void kernel_launch(void* const* d_in, const int* in_sizes, int n_in,
                              void* d_out, int out_size, void* d_ws, size_t ws_size,
                              hipStream_t stream) {
  const int M = BB * SS;                      // 8192
  const int* ids  = (const int*)d_in[0];
  const int* mask = (const int*)d_in[1];
  const float* emb = (const float*)d_in[2];
  const float* Wq = (const float*)d_in[3];  const float* bq = (const float*)d_in[4];
  const float* Wk = (const float*)d_in[5];  const float* bk = (const float*)d_in[6];
  const float* Wv = (const float*)d_in[7];  const float* bv = (const float*)d_in[8];
  const float* Wo = (const float*)d_in[9];  const float* bo = (const float*)d_in[10];
  const float* lg = (const float*)d_in[11]; const float* lb = (const float*)d_in[12];
  const float* W1 = (const float*)d_in[13]; const float* b1 = (const float*)d_in[14];
  const float* W2 = (const float*)d_in[15]; const float* b2 = (const float*)d_in[16];
  const float* Wp = (const float*)d_in[17]; const float* bp = (const float*)d_in[18];

  // workspace layout (bytes), all offsets 16B-aligned
  char* base = (char*)d_ws;
  const size_t SLOTF = (size_t)M * EE;        // elements per [M,E] matrix
  float* xf   = (float*)base;                          // f32   33.55 MB
  u16*  xbf   = (u16*)(base + SLOTF*4);                // bf16  16.78 MB
  u16*  qbf   = (u16*)(base + SLOTF*6);                // q,k,v contiguous (QKV-fused epilogue)
  u16*  kbf   = (u16*)(base + SLOTF*8);
  u16*  vbf   = (u16*)(base + SLOTF*10);
  u16*  ctxbf = (u16*)(base + SLOTF*12);
  u16*  c2bf  = qbf;                                   // q dead after attention
  u16*  hbf   = kbf;                                   // k dead after attention
  u16*  WqT   = (u16*)(base + SLOTF*14);               // WqT/WkT/WvT/WoT/W1T contiguous
  u16*  W1T   = WqT + (size_t)4*EE*EE;
  float* gsum = (float*)(W1T + (size_t)FF*EE);         // [B][F]
  float* w2wp = gsum + BB*FF;                          // [F][3]

  hipMemsetAsync(gsum, 0, BB*FF*sizeof(float), stream);

  embed_kernel<<<M, 256, 0, stream>>>(ids, emb, xf, xbf);

  prep_weights<<<8192, 256, 0, stream>>>(Wq, Wk, Wv, Wo, W1, WqT);
  w2wp_kernel<<<FF/8, 256, 0, stream>>>(W2, Wp, w2wp);

  // fused QKV: one dispatch, 1536 blocks
  gemm_mfma<2><<<dim3(3*EE/128, M/128), 256, 0, stream>>>(
      xbf, WqT, bq, bk, bv, qbf, nullptr, M, EE, EE);

  attn_mfma<<<dim3(SS/128, BB*HH), 256, 0, stream>>>(qbf, kbf, vbf, mask, ctxbf);

  gemm_mfma<0><<<dim3(EE/128, M/128), 256, 0, stream>>>(
      ctxbf, WqT + (size_t)3*EE*EE, bo, nullptr, nullptr, c2bf, nullptr, M, EE, EE);

  ln_kernel<<<M, 256, 0, stream>>>(c2bf, xf, lg, lb, hbf);

  gemm_mfma<1><<<dim3(FF/128, M/128), 256, 0, stream>>>(
      hbf, W1T, b1, nullptr, nullptr, nullptr, gsum, M, FF, EE);

  out_final<<<1, 256, 0, stream>>>(gsum, w2wp, b2, Wp, bp, (float*)d_out);
}